// Round 1
// baseline (664.731 us; speedup 1.0000x reference)
//
#include <hip/hip_runtime.h>
#include <math.h>

#define NUM_EMB 1024
#define EMB_DIM 256
#define N_ROWS  65536
#define HW      1024          // 32*32 spatial
#define QUANT_OFF 1
#define IDX_OFF   (1 + 16777216)
#define EPS_D 1e-12

// ---------------- kernel 1: normalize codebook rows (f32) ----------------
__global__ __launch_bounds__(256)
void k_norm_w(const float* __restrict__ w, float* __restrict__ wn) {
  const int k = blockIdx.x, t = threadIdx.x;
  float v = w[(size_t)k * EMB_DIM + t];
  float s = v * v;
  for (int o = 32; o; o >>= 1) s += __shfl_down(s, o);
  __shared__ float ps[4];
  if ((t & 63) == 0) ps[t >> 6] = s;
  __syncthreads();
  const float tot = ps[0] + ps[1] + ps[2] + ps[3];
  wn[(size_t)k * EMB_DIM + t] = v / fmaxf(sqrtf(tot), 1e-12f);
}

// ---------------- kernel 2: fp32 score GEMM + per-row top-2 ----------------
// block: 256 threads, 64 rows x all 1024 codes (8 code-tiles of 128, K-slabs of 64)
#define MR 64
#define CT 128
#define DK 64

__global__ __launch_bounds__(256)
void k_pass1(const float* __restrict__ x, const float* __restrict__ wn,
             int* __restrict__ idx1, int* __restrict__ idx2) {
  __shared__ __align__(16) float xs[DK][MR];      // 16 KB  [k][row]
  __shared__ __align__(16) float ws[DK][CT + 4];  // 33 KB  [k][code], pad 4
  const int t   = threadIdx.x;
  const int blk = blockIdx.x;
  const int b   = blk >> 4;              // 16 blocks per batch image
  const int hw0 = (blk & 15) * MR;
  const float* xbase = x + (size_t)b * (EMB_DIM * HW) + hw0;

  const int cg  = t & 15;                // code group: codes cg*4..+3 and 64+cg*4..+3
  const int rgg = t >> 4;                // row group: rows rgg*4..+3

  float t1v[4], t2v[4]; int t1i[4], t2i[4];
#pragma unroll
  for (int j = 0; j < 4; ++j) { t1v[j] = -INFINITY; t2v[j] = -INFINITY; t1i[j] = 0; t2i[j] = 1; }

  const int sr  = t & 63;                // x-staging row
  const int sd  = t >> 6;                // x-staging k phase
  const int wkl = (t & 15) * 4;          // w-staging k
  const int wcg = t >> 4;                // w-staging code phase

  for (int ct = 0; ct < 8; ++ct) {
    float acc[4][8];
#pragma unroll
    for (int a = 0; a < 4; ++a)
#pragma unroll
      for (int c = 0; c < 8; ++c) acc[a][c] = 0.f;

    for (int ks = 0; ks < 4; ++ks) {
      __syncthreads();
      // stage x chunk [64 k][64 rows] (coalesced 256B/wave; L2-resident on re-reads)
#pragma unroll
      for (int i = 0; i < 16; ++i) {
        const int kl = sd + i * 4;
        xs[kl][sr] = xbase[(size_t)(ks * DK + kl) * HW + sr];
      }
      // stage w slab [64 k][128 codes] (float4 global reads)
#pragma unroll
      for (int j = 0; j < 8; ++j) {
        const int cl = j * 16 + wcg;
        const float4 v = *(const float4*)&wn[(size_t)(ct * CT + cl) * EMB_DIM + ks * DK + wkl];
        ws[wkl + 0][cl] = v.x; ws[wkl + 1][cl] = v.y;
        ws[wkl + 2][cl] = v.z; ws[wkl + 3][cl] = v.w;
      }
      __syncthreads();
#pragma unroll 4
      for (int kk = 0; kk < DK; ++kk) {
        const float4 xa = *(const float4*)&xs[kk][rgg * 4];
        const float4 wa = *(const float4*)&ws[kk][cg * 4];
        const float4 wb = *(const float4*)&ws[kk][64 + cg * 4];
        const float ax[4] = {xa.x, xa.y, xa.z, xa.w};
        const float wv[8] = {wa.x, wa.y, wa.z, wa.w, wb.x, wb.y, wb.z, wb.w};
#pragma unroll
        for (int jr = 0; jr < 4; ++jr)
#pragma unroll
          for (int jc = 0; jc < 8; ++jc)
            acc[jr][jc] = fmaf(ax[jr], wv[jc], acc[jr][jc]);
      }
    }
    // merge this code-tile into running top-2 (ascending index order; strict > keeps first)
#pragma unroll
    for (int jr = 0; jr < 4; ++jr) {
#pragma unroll
      for (int jc = 0; jc < 8; ++jc) {
        const float v = acc[jr][jc];
        const int c = ct * CT + (jc >> 2) * 64 + cg * 4 + (jc & 3);
        if (v > t1v[jr]) { t2v[jr] = t1v[jr]; t2i[jr] = t1i[jr]; t1v[jr] = v; t1i[jr] = c; }
        else if (v > t2v[jr]) { t2v[jr] = v; t2i[jr] = c; }
      }
    }
  }

  // cross-thread top-2 per row (16 cg threads share each row)
  __syncthreads();
  float* cvals = &ws[0][0];                    // [64][16][2] floats
  int*   cinds = (int*)(&ws[0][0]) + 2048;     // [64][16][2] ints
#pragma unroll
  for (int jr = 0; jr < 4; ++jr) {
    const int row = rgg * 4 + jr;
    cvals[(row * 16 + cg) * 2 + 0] = t1v[jr];
    cvals[(row * 16 + cg) * 2 + 1] = t2v[jr];
    cinds[(row * 16 + cg) * 2 + 0] = t1i[jr];
    cinds[(row * 16 + cg) * 2 + 1] = t2i[jr];
  }
  __syncthreads();
  if (t < MR) {
    float b1 = -INFINITY, b2 = -INFINITY; int i1 = 0, i2 = 1;
    for (int g = 0; g < 16; ++g)
      for (int e = 0; e < 2; ++e) {
        const float v = cvals[(t * 16 + g) * 2 + e];
        const int  c = cinds[(t * 16 + g) * 2 + e];
        if (v > b1) { b2 = b1; i2 = i1; b1 = v; i1 = c; }
        else if (v > b2) { b2 = v; i2 = c; }
      }
    idx1[blk * MR + t] = i1;
    idx2[blk * MR + t] = i2;
  }
}

// ------- kernel 3: fp64 recheck of top-2, idx + loss + quant writes -------
__global__ __launch_bounds__(256)
void k_finish(const float* __restrict__ x, const float* __restrict__ w,
              const float* __restrict__ wn,
              const int* __restrict__ idx1, const int* __restrict__ idx2,
              float* __restrict__ out) {
  const int t = threadIdx.x;
  const int n = blockIdx.x * 256 + t;
  const int b = n >> 10;
  const float* xr = x + (size_t)b * (EMB_DIM * HW) + (n & 1023);
  const int c1 = idx1[n], c2 = idx2[n];
  const float* w1 = w + (size_t)c1 * EMB_DIM;
  const float* w2 = w + (size_t)c2 * EMB_DIM;
  double sxx = 0, s1 = 0, s2 = 0, w11 = 0, w22 = 0;
#pragma unroll 8
  for (int d = 0; d < EMB_DIM; ++d) {
    const double xv = (double)xr[(size_t)d * HW];
    const double a = (double)w1[d], bb = (double)w2[d];
    sxx = fma(xv, xv, sxx); s1 = fma(xv, a, s1); s2 = fma(xv, bb, s2);
    w11 = fma(a, a, w11);   w22 = fma(bb, bb, w22);
  }
  const double nx = fmax(sqrt(sxx), EPS_D);
  const double n1 = fmax(sqrt(w11), EPS_D);
  const double n2 = fmax(sqrt(w22), EPS_D);
  const double fn2 = sxx / (nx * nx);
  const double d1 = fn2 + w11 / (n1 * n1) - 2.0 * s1 / (nx * n1);
  const double d2 = fn2 + w22 / (n2 * n2) - 2.0 * s2 / (nx * n2);
  int cw; double dmin;
  if (d2 < d1 || (d2 == d1 && c2 < c1)) { cw = c2; dmin = d2; }
  else                                  { cw = c1; dmin = d1; }
  out[IDX_OFF + n] = (float)cw;

  // loss = 1.25 * sum(dist_min) / (N*D)
  double v = dmin;
  for (int o = 32; o; o >>= 1) v += __shfl_down(v, o);
  __shared__ double wps[4];
  if ((t & 63) == 0) wps[t >> 6] = v;
  __syncthreads();
  if (t == 0) {
    const double s = wps[0] + wps[1] + wps[2] + wps[3];
    atomicAdd(out, (float)(1.25 * s / 16777216.0));
  }

  // quant: out[b, d, hw] = wn[cw][d]; lane-contiguous 1KB stores per d
  const int hw0 = (blockIdx.x & 3) * 256;
  float* qout = out + QUANT_OFF + (size_t)(blockIdx.x >> 2) * (EMB_DIM * HW) + hw0;
  const float* wrow = wn + (size_t)cw * EMB_DIM;
#pragma unroll 4
  for (int d = 0; d < EMB_DIM; ++d) {
    qout[(size_t)d * HW + t] = wrow[d];
  }
}

extern "C" void kernel_launch(void* const* d_in, const int* in_sizes, int n_in,
                              void* d_out, int out_size, void* d_ws, size_t ws_size,
                              hipStream_t stream) {
  const float* x = (const float*)d_in[0];   // [64,256,32,32]
  const float* w = (const float*)d_in[1];   // [1024,256]
  float* out = (float*)d_out;               // [1 + 16777216 + 65536] f32
  float* wn  = (float*)d_ws;                                  // 1 MB
  int* idx1 = (int*)((char*)d_ws + (size_t)NUM_EMB * EMB_DIM * sizeof(float));
  int* idx2 = idx1 + N_ROWS;

  hipMemsetAsync(d_out, 0, sizeof(float), stream);  // zero loss accumulator
  hipLaunchKernelGGL(k_norm_w, dim3(NUM_EMB), dim3(256), 0, stream, w, wn);
  hipLaunchKernelGGL(k_pass1, dim3(N_ROWS / MR), dim3(256), 0, stream, x, wn, idx1, idx2);
  hipLaunchKernelGGL(k_finish, dim3(N_ROWS / 256), dim3(256), 0, stream, x, w, wn, idx1, idx2, out);
}

// Round 2
// 256.074 us; speedup vs baseline: 2.5959x; 2.5959x over previous
//
#include <hip/hip_runtime.h>
#include <math.h>

#define NUM_EMB 1024
#define EMB_DIM 256
#define N_ROWS  65536
#define HW      1024
#define QUANT_OFF 1
#define IDX_OFF   (1 + 16777216)
#define LDA 264   // halfs per A-row in LDS (256 + 8 pad -> 528B, 16B-aligned, ~2-way banks)

typedef unsigned int uint;
typedef _Float16 f16x8 __attribute__((ext_vector_type(8)));
typedef float    f32x4 __attribute__((ext_vector_type(4)));

__device__ __forceinline__ uint umin2(uint a, uint b) { return a < b ? a : b; }
__device__ __forceinline__ uint umax2(uint a, uint b) { return a > b ? a : b; }

// ---------------- kernel 1: normalize codebook (f32 + f16 copies) ----------------
__global__ __launch_bounds__(256)
void k_norm_w(const float* __restrict__ w, float* __restrict__ wn, _Float16* __restrict__ wh) {
  const int k = blockIdx.x, t = threadIdx.x;
  const float v = w[(size_t)k * EMB_DIM + t];
  float s = v * v;
  for (int o = 32; o; o >>= 1) s += __shfl_down(s, o);
  __shared__ float ps[4];
  if ((t & 63) == 0) ps[t >> 6] = s;
  __syncthreads();
  const float tot = ps[0] + ps[1] + ps[2] + ps[3];
  const float nv = v / fmaxf(sqrtf(tot), 1e-12f);
  wn[(size_t)k * EMB_DIM + t] = nv;
  wh[(size_t)k * EMB_DIM + t] = (_Float16)nv;
}

// ---------------- kernel 2: fp16 MFMA score GEMM + per-row top-4 candidates ----------------
// 256 thr (4 waves), 64 rows/block, 4 chunks of 256 codes (wave w owns codes w*64..+64 per chunk).
// A: LDS full-K fp16 (staged once). B: direct global fp16 fragment loads (L1/L2 resident).
__global__ __launch_bounds__(256, 2)
void k_pass1(const float* __restrict__ x, const _Float16* __restrict__ wh,
             uint* __restrict__ cand) {
  __shared__ __align__(16) _Float16 As[64 * LDA];   // 33792 B
  const int t = threadIdx.x;
  const int blk = blockIdx.x;
  const int b = blk >> 4;
  const int hw0 = (blk & 15) * 64;

  // ---- stage A: x[b, d, hw0+r] f32 -> As[r][d] f16 (transpose via scalar ds_write_b16) ----
  {
    const int lhw = t & 63;          // local row
    const int ph = t >> 6;           // d phase
    const float* xb = x + (size_t)b * (EMB_DIM * HW) + hw0 + lhw;
#pragma unroll 8
    for (int j = 0; j < 64; ++j) {
      const int d = ph + j * 4;
      As[lhw * LDA + d] = (_Float16)xb[(size_t)d * HW];
    }
  }
  __syncthreads();

  const int lane = t & 63;
  const int q = lane >> 4;        // quad
  const int l15 = lane & 15;
  const int w = t >> 6;           // wave id

  uint t1[16], t2[16];            // per-(lane,row-slot) running top-2 packed keys
#pragma unroll
  for (int i = 0; i < 16; ++i) { t1[i] = 0u; t2[i] = 0u; }

  // per-lane B base: code = (chunk*256 + w*64 + ct*16 + l15), k = ks*32 + q*8
  const _Float16* pb = wh + (size_t)(w * 64 + l15) * EMB_DIM + q * 8;

  for (int c4 = 0; c4 < 4; ++c4) {
    f32x4 acc[4][4];
#pragma unroll
    for (int rt = 0; rt < 4; ++rt)
#pragma unroll
      for (int ct = 0; ct < 4; ++ct) acc[rt][ct] = (f32x4)0.f;

    const _Float16* pc[4];
#pragma unroll
    for (int ct = 0; ct < 4; ++ct) pc[ct] = pb + (size_t)(c4 * 256 + ct * 16) * EMB_DIM;

    f16x8 bcur[4], acur[4], bnxt[4], anxt[4];
#pragma unroll
    for (int ct = 0; ct < 4; ++ct) bcur[ct] = *(const f16x8*)(pc[ct]);
#pragma unroll
    for (int rt = 0; rt < 4; ++rt) acur[rt] = *(const f16x8*)&As[(rt * 16 + l15) * LDA + q * 8];

#pragma unroll
    for (int ks = 0; ks < 8; ++ks) {
      if (ks < 7) {
        const int off = (ks + 1) * 32;
#pragma unroll
        for (int ct = 0; ct < 4; ++ct) bnxt[ct] = *(const f16x8*)(pc[ct] + off);
#pragma unroll
        for (int rt = 0; rt < 4; ++rt) anxt[rt] = *(const f16x8*)&As[(rt * 16 + l15) * LDA + off + q * 8];
      }
#pragma unroll
      for (int rt = 0; rt < 4; ++rt)
#pragma unroll
        for (int ct = 0; ct < 4; ++ct)
          acc[rt][ct] = __builtin_amdgcn_mfma_f32_16x16x32_f16(acur[rt], bcur[ct], acc[rt][ct], 0, 0, 0);
      if (ks < 7) {
#pragma unroll
        for (int i = 0; i < 4; ++i) { bcur[i] = bnxt[i]; acur[i] = anxt[i]; }
      }
    }

    // epilogue: pack score -> ordered key with idx in low 10 bits, merge into top-2
    uint idxv[4];
#pragma unroll
    for (int ct = 0; ct < 4; ++ct) idxv[ct] = (uint)(c4 * 256 + w * 64 + ct * 16 + l15);
#pragma unroll
    for (int rt = 0; rt < 4; ++rt)
#pragma unroll
      for (int ct = 0; ct < 4; ++ct)
#pragma unroll
        for (int r = 0; r < 4; ++r) {
          const float v = fmaxf(acc[rt][ct][r], 0.0f);     // negatives -> 0 (never the argmax)
          const uint key = (__float_as_uint(v) & 0xFFFFFC00u) | idxv[ct];
          const int slot = rt * 4 + r;
          const uint lo = umin2(key, t1[slot]);
          t1[slot] = umax2(key, t1[slot]);
          t2[slot] = umax2(t2[slot], lo);
        }
  }

  // ---- block-level per-row top-4 (reuse A LDS as key scratch) ----
  __syncthreads();
  uint* keys = (uint*)As;   // [64 rows][128 keys]
#pragma unroll
  for (int slot = 0; slot < 16; ++slot) {
    const int rt = slot >> 2, r = slot & 3;
    const int row = rt * 16 + q * 4 + r;
    const int col = w * 32 + l15 * 2;
    keys[row * 128 + col] = t1[slot];
    keys[row * 128 + col + 1] = t2[slot];
  }
  __syncthreads();
  {
    const int row = t >> 2, seg = t & 3;     // 4 threads per row, 32 keys each
    uint s1 = 0, s2 = 0;
#pragma unroll
    for (int i = 0; i < 8; ++i) {
      const int ii = (i + t) & 7;            // rotate start for bank spread
      const uint4 k4 = *(const uint4*)&keys[row * 128 + seg * 32 + ii * 4];
      const uint kk[4] = {k4.x, k4.y, k4.z, k4.w};
#pragma unroll
      for (int e = 0; e < 4; ++e) {
        const uint lo = umin2(kk[e], s1);
        s1 = umax2(kk[e], s1);
        s2 = umax2(s2, lo);
      }
    }
    __syncthreads();
    keys[t * 2] = s1;        // mini[row][seg][2] == keys[2t]
    keys[t * 2 + 1] = s2;
  }
  __syncthreads();
  if (t < 64) {
    uint c0 = 0, c1 = 0, c2 = 0, c3 = 0;     // sorted desc
#pragma unroll
    for (int i = 0; i < 8; ++i) {
      const uint k = keys[t * 8 + i];
      const uint n0 = umin2(c0, k); c0 = umax2(c0, k);
      const uint n1 = umin2(c1, n0); c1 = umax2(c1, n0);
      const uint n2 = umin2(c2, n1); c2 = umax2(c2, n1);
      c3 = umax2(c3, n2);
    }
    uint4 o; o.x = c0; o.y = c1; o.z = c2; o.w = c3;
    *(uint4*)&cand[(size_t)(blk * 64 + t) * 4] = o;
  }
}

// ------- kernel 3: fp64 recheck of top-4, idx + loss + quant writes -------
__global__ __launch_bounds__(256)
void k_finish(const float* __restrict__ x, const float* __restrict__ w,
              const float* __restrict__ wn, const uint* __restrict__ cand,
              float* __restrict__ out) {
  const int t = threadIdx.x;
  const int n = blockIdx.x * 256 + t;
  const int b = n >> 10;
  const float* xr = x + (size_t)b * (EMB_DIM * HW) + (n & 1023);
  const uint4 ck = *(const uint4*)&cand[(size_t)n * 4];
  const int ci[4] = {(int)(ck.x & 1023u), (int)(ck.y & 1023u),
                     (int)(ck.z & 1023u), (int)(ck.w & 1023u)};
  const float* wp0 = w + (size_t)ci[0] * EMB_DIM;
  const float* wp1 = w + (size_t)ci[1] * EMB_DIM;
  const float* wp2 = w + (size_t)ci[2] * EMB_DIM;
  const float* wp3 = w + (size_t)ci[3] * EMB_DIM;

  double sxx = 0.0;
  double s0 = 0, s1 = 0, s2 = 0, s3 = 0;
  double a0 = 0, a1 = 0, a2 = 0, a3 = 0;   // |w|^2 accumulators
#pragma unroll 2
  for (int d = 0; d < EMB_DIM; d += 4) {
    const float4 w40 = *(const float4*)&wp0[d];
    const float4 w41 = *(const float4*)&wp1[d];
    const float4 w42 = *(const float4*)&wp2[d];
    const float4 w43 = *(const float4*)&wp3[d];
    const float xf[4] = {xr[(size_t)(d + 0) * HW], xr[(size_t)(d + 1) * HW],
                         xr[(size_t)(d + 2) * HW], xr[(size_t)(d + 3) * HW]};
    const float wf0[4] = {w40.x, w40.y, w40.z, w40.w};
    const float wf1[4] = {w41.x, w41.y, w41.z, w41.w};
    const float wf2[4] = {w42.x, w42.y, w42.z, w42.w};
    const float wf3[4] = {w43.x, w43.y, w43.z, w43.w};
#pragma unroll
    for (int e = 0; e < 4; ++e) {
      const double xv = (double)xf[e];
      sxx = fma(xv, xv, sxx);
      const double v0 = (double)wf0[e], v1 = (double)wf1[e];
      const double v2 = (double)wf2[e], v3 = (double)wf3[e];
      s0 = fma(xv, v0, s0); a0 = fma(v0, v0, a0);
      s1 = fma(xv, v1, s1); a1 = fma(v1, v1, a1);
      s2 = fma(xv, v2, s2); a2 = fma(v2, v2, a2);
      s3 = fma(xv, v3, s3); a3 = fma(v3, v3, a3);
    }
  }
  const double nx = fmax(sqrt(sxx), 1e-12);
  const double fn2 = sxx / (nx * nx);
  const double sd[4] = {s0, s1, s2, s3};
  const double ad[4] = {a0, a1, a2, a3};
  double dmin = 1e300; int cw = 1 << 30;
#pragma unroll
  for (int j = 0; j < 4; ++j) {
    const double nw = fmax(sqrt(ad[j]), 1e-12);
    const double dj = fn2 + ad[j] / (nw * nw) - 2.0 * sd[j] / (nx * nw);
    if (dj < dmin || (dj == dmin && ci[j] < cw)) { dmin = dj; cw = ci[j]; }
  }
  out[IDX_OFF + n] = (float)cw;

  // loss = 1.25 * sum(dist_min) / (N*D)
  double v = dmin;
  for (int o = 32; o; o >>= 1) v += __shfl_down(v, o);
  __shared__ double wps[4];
  if ((t & 63) == 0) wps[t >> 6] = v;
  __syncthreads();
  if (t == 0) {
    const double s = wps[0] + wps[1] + wps[2] + wps[3];
    atomicAdd(out, (float)(1.25 * s / 16777216.0));
  }

  // quant: out[b, d, hw] = wn[cw][d]; 1KB coalesced stores per d
  const int hw0 = (blockIdx.x & 3) * 256;
  float* qout = out + QUANT_OFF + (size_t)(blockIdx.x >> 2) * (EMB_DIM * HW) + hw0;
  const float* wrow = wn + (size_t)cw * EMB_DIM;
#pragma unroll 4
  for (int d = 0; d < EMB_DIM; ++d) {
    qout[(size_t)d * HW + t] = wrow[d];
  }
}

extern "C" void kernel_launch(void* const* d_in, const int* in_sizes, int n_in,
                              void* d_out, int out_size, void* d_ws, size_t ws_size,
                              hipStream_t stream) {
  const float* x = (const float*)d_in[0];   // [64,256,32,32]
  const float* w = (const float*)d_in[1];   // [1024,256]
  float* out = (float*)d_out;               // [1 + 16777216 + 65536] f32

  char* ws = (char*)d_ws;
  float*     wn   = (float*)ws;                                   // 1 MB
  _Float16*  wh   = (_Float16*)(ws + 1048576);                    // 512 KB
  uint*      cand = (uint*)(ws + 1048576 + 524288);               // 1 MB

  hipMemsetAsync(d_out, 0, sizeof(float), stream);  // zero loss accumulator
  hipLaunchKernelGGL(k_norm_w, dim3(NUM_EMB), dim3(256), 0, stream, w, wn, wh);
  hipLaunchKernelGGL(k_pass1, dim3(N_ROWS / 64), dim3(256), 0, stream, x, wh, cand);
  hipLaunchKernelGGL(k_finish, dim3(N_ROWS / 256), dim3(256), 0, stream, x, w, wn, cand, out);
}